// Round 6
// baseline (288.599 us; speedup 1.0000x reference)
//
#include <hip/hip_runtime.h>
#include <hip/hip_bf16.h>

// Dynamic per-tensor symmetric int8 quantized GEMM (AQT-style).
//   bound = max(absmax(x), 1e-6); scale = 127/bound
//   q = clip(rint(x*scale), -127, 127)  (int8)
//   out = (q_lhs @ q_rhs) * bound_l*bound_r/127^2   (fp32)
//
// R9: GEMM B-operand moved from LDS to registers.
//   - quant-rhs now emits chunked-B layout qB2[n/32][kchunk][row32][16B]
//     (addr(n,kk) = (n>>5)*131072 + (kk>>4)*512 + (n&31)*16 + (kk&15)),
//     so each wave B-fragment is ONE coalesced 1024B global_load_dwordx4.
//   - gemm: As-only LDS (64KB dbuf), 2 phases/tile (2 barriers vs 8),
//     B(t+1) prefetched into ping-pong reg sets (unroll-2, named), drained
//     by the end-of-tile vmcnt(0). LDS pipe 2304->1536 cyc/tile < MFMA 2342.
//   - DIAGNOSTIC: absmax launched twice (idempotent);
//     Dtotal - Dgemm = absmax cost -> decomposes the invariant 172us gap.

typedef int v4i __attribute__((ext_vector_type(4)));
typedef int v16i __attribute__((ext_vector_type(16)));

#define MAT_N 4096

__device__ __forceinline__ void async_copy16(const void* g, void* l) {
    __builtin_amdgcn_global_load_lds(
        (const __attribute__((address_space(1))) void*)g,
        (__attribute__((address_space(3))) void*)l,
        16, 0, 0);
}

__device__ __forceinline__ unsigned uabs_bits(float f) {
    return __float_as_uint(f) & 0x7fffffffu;
}

// ---- absmax partials: blocks [0,512) lhs, [512,1024) rhs; pmax[b] plain store
__global__ __launch_bounds__(256) void absmax_partial_kernel(
    const float4* __restrict__ lhs, const float4* __restrict__ rhs,
    unsigned* __restrict__ pmax) {
    const int b = blockIdx.x;
    const float4* x = (b < 512) ? lhs : rhs;
    const float4* p = x + (size_t)(b & 511) * 8192;
    unsigned m0 = 0, m1 = 0, m2 = 0, m3 = 0;
#pragma unroll 8
    for (int u = 0; u < 32; u++) {
        float4 v = p[u * 256 + threadIdx.x];
        m0 = max(m0, uabs_bits(v.x));
        m1 = max(m1, uabs_bits(v.y));
        m2 = max(m2, uabs_bits(v.z));
        m3 = max(m3, uabs_bits(v.w));
    }
    unsigned m = max(max(m0, m1), max(m2, m3));
#pragma unroll
    for (int off = 32; off > 0; off >>= 1)
        m = max(m, (unsigned)__shfl_down(m, off, 64));
    __shared__ unsigned sm[4];
    if ((threadIdx.x & 63) == 0) sm[threadIdx.x >> 6] = m;
    __syncthreads();
    if (threadIdx.x == 0)
        pmax[b] = max(max(sm[0], sm[1]), max(sm[2], sm[3]));
}

// ---- fused quantize: blocks [0,4096) lhs passthrough;
// blocks [4096,5120) rhs -> chunked-B2 layout (full-line coalesced writes).
__global__ __launch_bounds__(256) void quant_fused_kernel(
    const float* __restrict__ lhs, const float* __restrict__ rhs,
    unsigned char* __restrict__ qA, signed char* __restrict__ qB2,
    const unsigned* __restrict__ pmax) {
    const int N = MAT_N;
    const int t = threadIdx.x;
    int b = blockIdx.x;
    // [64 n-rows][256 k-bytes]; 16B chunks XOR-swizzled by (nr&15)
    __shared__ __align__(16) signed char smT[64 * 256];
    __shared__ unsigned red[4];
    __shared__ float s_sh;

    // Reduce this tensor's 512 partials -> scale (L2-hot, ~2KB)
    const int slot0 = (b < 4096) ? 0 : 512;
    unsigned mm = max(pmax[slot0 + t], pmax[slot0 + 256 + t]);
#pragma unroll
    for (int off = 32; off > 0; off >>= 1)
        mm = max(mm, (unsigned)__shfl_down(mm, off, 64));
    if ((t & 63) == 0) red[t >> 6] = mm;
    __syncthreads();
    if (t == 0) {
        unsigned f = max(max(red[0], red[1]), max(red[2], red[3]));
        s_sh = 127.0f / fmaxf(__uint_as_float(f), 1e-6f);
    }
    __syncthreads();
    const float s = s_sh;

    if (b < 4096) {
        const float4* x4 = (const float4*)lhs;
        unsigned* q4 = (unsigned*)qA;
        const int base4 = b * 1024;
#pragma unroll
        for (int u = 0; u < 4; u++) {
            int idx = base4 + u * 256 + t;
            float4 v = x4[idx];
            int a = min(127, max(-127, (int)rintf(v.x * s)));
            int bq = min(127, max(-127, (int)rintf(v.y * s)));
            int c = min(127, max(-127, (int)rintf(v.z * s)));
            int d = min(127, max(-127, (int)rintf(v.w * s)));
            q4[idx] = (unsigned)(a & 0xff) | ((unsigned)(bq & 0xff) << 8) |
                      ((unsigned)(c & 0xff) << 16) | ((unsigned)(d & 0xff) << 24);
        }
    } else {
        // rhs: tile = 256 k-rows x 64 n-cols -> chunked-B2 layout
        const int rb = b - 4096;          // 0..1023
        const int n0 = (rb & 63) * 64;    // column origin (floats)
        const int k0 = (rb >> 6) * 256;   // row origin
        const int mk = t >> 4;            // 0..15
        const int mn = t & 15;            // 0..15
        const float4* x4 = (const float4*)rhs;

        // Load all 16 float4 (4 sub-tiles x 4 rows) back-to-back
        float4 v[4][4];
#pragma unroll
        for (int ss = 0; ss < 4; ss++)
#pragma unroll
            for (int i = 0; i < 4; i++)
                v[ss][i] = x4[(size_t)(k0 + 64 * ss + 4 * mk + i) * (N / 4) +
                              (n0 >> 2) + mn];

        // Quantize + pack to 16 dwords
        unsigned w[4][4];
#pragma unroll
        for (int ss = 0; ss < 4; ss++)
#pragma unroll
            for (int i = 0; i < 4; i++) {
                int a = min(127, max(-127, (int)rintf(v[ss][i].x * s)));
                int bq = min(127, max(-127, (int)rintf(v[ss][i].y * s)));
                int c = min(127, max(-127, (int)rintf(v[ss][i].z * s)));
                int d = min(127, max(-127, (int)rintf(v[ss][i].w * s)));
                w[ss][i] =
                    (unsigned)(a & 0xff) | ((unsigned)(bq & 0xff) << 8) |
                    ((unsigned)(c & 0xff) << 16) | ((unsigned)(d & 0xff) << 24);
            }

        // 4x4 byte transpose per sub-tile; write dwords into swizzled smT.
        // Logical dword col = 16*ss + mk; chunk cq = col>>2, off = col&3.
        // Phys chunk = cq ^ (nr & 15).
#pragma unroll
        for (int ss = 0; ss < 4; ss++) {
            const int cq = 4 * ss + (mk >> 2);
            const int off = (mk & 3) * 4;
#pragma unroll
            for (int j = 0; j < 4; j++) {
                unsigned selj = (unsigned)j | ((unsigned)(4 + j) << 8) |
                                ((unsigned)j << 16) | ((unsigned)(4 + j) << 24);
                unsigned p01 = __builtin_amdgcn_perm(w[ss][1], w[ss][0], selj);
                unsigned p23 = __builtin_amdgcn_perm(w[ss][3], w[ss][2], selj);
                unsigned uj = __builtin_amdgcn_perm(p23, p01, 0x05040100u);
                const int nr = 4 * mn + j;
                *(unsigned*)(smT + nr * 256 + ((cq ^ (nr & 15)) << 4) + off) = uj;
            }
        }
        __syncthreads();

        // Emit chunked-B2: addr = (n>>5)*131072 + (kk>>4)*512 + (n&31)*16.
        // Consecutive threads -> contiguous 16B -> full 256B-line writes.
#pragma unroll
        for (int wq = 0; wq < 4; wq++) {
            const int idx = wq * 256 + t;     // 0..1023
            const int row = idx & 31;         // n-row within 32-block
            const int ql = (idx >> 5) & 15;   // k-chunk within tile
            const int nb = idx >> 9;          // n 32-block within 64
            const int nr = nb * 32 + row;     // LDS n-row
            int4 val = *(const int4*)(smT + nr * 256 + ((ql ^ (nr & 15)) << 4));
            *(int4*)(qB2 + (size_t)((n0 >> 5) + nb) * 131072 +
                     (size_t)((k0 >> 4) + ql) * 512 + row * 16) = val;
        }
    }
}

#define MFMA_I8 __builtin_amdgcn_mfma_i32_32x32x32_i8
#define SBAR0() __builtin_amdgcn_sched_barrier(0)
#define BARRIER() __builtin_amdgcn_s_barrier()

// ---- int8 MFMA GEMM: C = A(MxK) * B2 (chunked layout), 256x256 tile,
// BK=128, 8 waves (2Mx4N). A: LDS dbuf (64KB) via global_load_lds +
// chunk swizzle. B: registers, prefetched one tile ahead from qB2 with
// fully-coalesced 1024B loads (no LDS, no swizzle). 2 phases per tile.
__global__ __launch_bounds__(512, 2) void gemm_i8_kernel(
    const signed char* __restrict__ A, const signed char* __restrict__ B2,
    float* __restrict__ C, const unsigned* __restrict__ pmax) {
    const int N = MAT_N;
    __shared__ __align__(16) signed char As[2][256 * 128];
    __shared__ unsigned redl[8], redr[8];

    const int tid = threadIdx.x;
    const int wave = tid >> 6;   // 0..7
    const int lane = tid & 63;
    const int m32 = lane & 31;   // row/col within a 32-tile
    const int h = lane >> 5;     // k-half selector
    const int wm = wave >> 2;    // 0..1 -> 128-row half of the M-tile
    const int wn = wave & 3;     // 0..3 -> 64-col quarter of the N-tile

    // XCD-aware swizzle: 256 blocks -> 16x16 grid; XCD x owns a 4x8 rect.
    const int bid = blockIdx.x;
    const int xcd = bid & 7;
    const int bi = bid >> 3;                 // 0..31 within XCD
    const int by = (xcd >> 1) * 4 + (bi >> 3);
    const int bx = (xcd & 1) * 8 + (bi & 7);
    const int brow = by * 256;
    const int bcol = bx * 256;

    v16i acc[4][2] = {};

    // A staging: 2048 16B-chunks per 256x128 tile; 4 chunks/thread.
    // LDS slot c=(r=c>>3, q'=c&7) receives global chunk q = q' ^ v(r).
    int gaoff[4], lofs[4];
#pragma unroll
    for (int u = 0; u < 4; u++) {
        int c = tid + 512 * u;
        int r = c >> 3;
        int q = (c & 7) ^ ((r ^ (r >> 3)) & 7);
        gaoff[u] = (brow + r) * N + q * 16;
        lofs[u] = c * 16;
    }

    // A fragment row bases + swizzle keys (k-invariant)
    int arow[4], av[4];
#pragma unroll
    for (int mi = 0; mi < 4; mi++) {
        int r = wm * 128 + mi * 32 + m32;
        arow[mi] = r * 128;
        av[mi] = (r ^ (r >> 3)) & 7;
    }
    // B2 per-lane base: (nblk)*131072 + m32*16 + h*512
    size_t b2b[2];
#pragma unroll
    for (int nj = 0; nj < 2; nj++)
        b2b[nj] = (size_t)((bcol + wn * 64 + nj * 32) >> 5) * 131072 +
                  m32 * 16 + h * 512;

    v4i bA_[2][4], bB_[2][4];  // ping-pong B reg sets [nj][s]

    // Prologue: stage A(0), load B(0) -> bA_, drain, barrier.
#pragma unroll
    for (int u = 0; u < 4; u++) async_copy16(A + gaoff[u], &As[0][lofs[u]]);
#pragma unroll
    for (int nj = 0; nj < 2; nj++)
#pragma unroll
        for (int s = 0; s < 4; s++)
            bA_[nj][s] = *(const v4i*)(B2 + b2b[nj] + s * 1024);
    asm volatile("s_waitcnt vmcnt(0)" ::: "memory");
    BARRIER();
    SBAR0();

    auto tile_body = [&](int t, v4i (&bC)[2][4], v4i (&bN)[2][4], bool ldn) {
        const signed char* as_ = As[t & 1];
        signed char* na = As[(t & 1) ^ 1];
        if (ldn) {
#pragma unroll
            for (int u = 0; u < 4; u++)
                async_copy16(A + gaoff[u] + (t + 1) * 128, na + lofs[u]);
#pragma unroll
            for (int nj = 0; nj < 2; nj++)
#pragma unroll
                for (int s = 0; s < 4; s++)
                    bN[nj][s] = *(const v4i*)(B2 + b2b[nj] +
                                              (size_t)(t + 1) * 4096 + s * 1024);
        }
        // phase 0: k-chunks s={0,1}
        {
            v4i a[4][2];
#pragma unroll
            for (int mi = 0; mi < 4; mi++)
#pragma unroll
                for (int s = 0; s < 2; s++)
                    a[mi][s] = *(const v4i*)(as_ + arow[mi] +
                                             (((2 * s + h) ^ av[mi]) << 4));
            asm volatile("s_waitcnt lgkmcnt(0)" ::: "memory");
            SBAR0();
            __builtin_amdgcn_s_setprio(1);
#pragma unroll
            for (int s = 0; s < 2; s++)
#pragma unroll
                for (int mi = 0; mi < 4; mi++)
#pragma unroll
                    for (int nj = 0; nj < 2; nj++)
                        acc[mi][nj] =
                            MFMA_I8(a[mi][s], bC[nj][s], acc[mi][nj], 0, 0, 0);
            __builtin_amdgcn_s_setprio(0);
            BARRIER();
        }
        // phase 1: k-chunks s={2,3}; end-of-tile drain (counted-by-distance)
        {
            v4i a[4][2];
#pragma unroll
            for (int mi = 0; mi < 4; mi++)
#pragma unroll
                for (int s = 0; s < 2; s++)
                    a[mi][s] = *(const v4i*)(as_ + arow[mi] +
                                             (((2 * (s + 2) + h) ^ av[mi]) << 4));
            asm volatile("s_waitcnt lgkmcnt(0)" ::: "memory");
            SBAR0();
            __builtin_amdgcn_s_setprio(1);
#pragma unroll
            for (int s = 0; s < 2; s++)
#pragma unroll
                for (int mi = 0; mi < 4; mi++)
#pragma unroll
                    for (int nj = 0; nj < 2; nj++)
                        acc[mi][nj] = MFMA_I8(a[mi][s], bC[nj][s + 2],
                                              acc[mi][nj], 0, 0, 0);
            __builtin_amdgcn_s_setprio(0);
            // waits A(t+1) stage + B(t+1) regs, issued ~1 tile (~2000cy) ago
            asm volatile("s_waitcnt vmcnt(0)" ::: "memory");
            BARRIER();
            SBAR0();
        }
    };

    for (int tt = 0; tt < 16; ++tt) {
        tile_body(2 * tt, bA_, bB_, true);
        tile_body(2 * tt + 1, bB_, bA_, tt < 15);
    }

    // Dequant scales from the 1024 partials (512 lhs, 512 rhs)
    unsigned ml = pmax[tid];
    unsigned mr = pmax[512 + tid];
#pragma unroll
    for (int off = 32; off > 0; off >>= 1) {
        ml = max(ml, (unsigned)__shfl_down(ml, off, 64));
        mr = max(mr, (unsigned)__shfl_down(mr, off, 64));
    }
    if (lane == 0) { redl[wave] = ml; redr[wave] = mr; }
    __syncthreads();
    unsigned fl = redl[0], fr = redr[0];
#pragma unroll
    for (int k = 1; k < 8; k++) {
        fl = max(fl, redl[k]);
        fr = max(fr, redr[k]);
    }
    const float bl = fmaxf(__uint_as_float(fl), 1e-6f);
    const float br = fmaxf(__uint_as_float(fr), 1e-6f);
    const float dq = bl * br * (1.0f / (127.0f * 127.0f));

    // C/D layout (32x32): col = lane&31, row = (reg&3) + 8*(reg>>2) + 4*h
#pragma unroll
    for (int mi = 0; mi < 4; mi++)
#pragma unroll
        for (int nj = 0; nj < 2; nj++) {
            const int col = bcol + wn * 64 + nj * 32 + m32;
#pragma unroll
            for (int reg = 0; reg < 16; reg++) {
                const int row =
                    brow + wm * 128 + mi * 32 + (reg & 3) + 8 * (reg >> 2) + 4 * h;
                C[(size_t)row * N + col] = (float)acc[mi][nj][reg] * dq;
            }
        }
}

extern "C" void kernel_launch(void* const* d_in, const int* in_sizes, int n_in,
                              void* d_out, int out_size, void* d_ws, size_t ws_size,
                              hipStream_t stream) {
    const float* lhs = (const float*)d_in[0];
    const float* rhs = (const float*)d_in[1];
    float* out = (float*)d_out;

    unsigned* pmax = (unsigned*)d_ws;  // 1024 partials (all written each call)
    signed char* qA = (signed char*)d_ws + 8192;
    signed char* qB2 = qA + (size_t)MAT_N * MAT_N;

    absmax_partial_kernel<<<1024, 256, 0, stream>>>(
        (const float4*)lhs, (const float4*)rhs, pmax);
    // DIAGNOSTIC duplicate (idempotent): Dtotal - Dgemm = absmax cost.
    absmax_partial_kernel<<<1024, 256, 0, stream>>>(
        (const float4*)lhs, (const float4*)rhs, pmax);
    quant_fused_kernel<<<5120, 256, 0, stream>>>(
        lhs, rhs, (unsigned char*)qA, qB2, pmax);
    gemm_i8_kernel<<<256, 512, 0, stream>>>(qA, qB2, out, pmax);
}

// Round 7
// 261.933 us; speedup vs baseline: 1.1018x; 1.1018x over previous
//
#include <hip/hip_runtime.h>
#include <hip/hip_bf16.h>

// Dynamic per-tensor symmetric int8 quantized GEMM (AQT-style).
//   bound = max(absmax(x), 1e-6); scale = 127/bound
//   q = clip(rint(x*scale), -127, 127)  (int8)
//   out = (q_lhs @ q_rhs) * bound_l*bound_r/127^2   (fp32)
//
// R10: fine-phases x counted-vmcnt (the untried m218 cell).
//   - gemm: R8's 4-phase structure, but A triple-buffered (3x32KB) +
//     B double-buffered (2x32KB) = 160KB LDS exactly. Per tile t:
//     phase0 issues stage B(t+1), phase1 issues stage A(t+2); end-of-tile
//     s_waitcnt vmcnt(4) waits A(t+1)+B(t+1), leaves A(t+2) IN FLIGHT
//     across the barrier (never drains to 0 until the t=30 tail).
//   - epilogue reduction arrays live in dead As space (LDS budget exact).
//   - absmax single launch (R9 diagnostic showed absmax = 13us, at floor).
//   - quant = R8 version verbatim (full 256B-line writes).

typedef int v4i __attribute__((ext_vector_type(4)));
typedef int v16i __attribute__((ext_vector_type(16)));

#define MAT_N 4096

__device__ __forceinline__ void async_copy16(const void* g, void* l) {
    __builtin_amdgcn_global_load_lds(
        (const __attribute__((address_space(1))) void*)g,
        (__attribute__((address_space(3))) void*)l,
        16, 0, 0);
}

__device__ __forceinline__ unsigned uabs_bits(float f) {
    return __float_as_uint(f) & 0x7fffffffu;
}

// ---- absmax partials: blocks [0,512) lhs, [512,1024) rhs; pmax[b] plain store
__global__ __launch_bounds__(256) void absmax_partial_kernel(
    const float4* __restrict__ lhs, const float4* __restrict__ rhs,
    unsigned* __restrict__ pmax) {
    const int b = blockIdx.x;
    const float4* x = (b < 512) ? lhs : rhs;
    const float4* p = x + (size_t)(b & 511) * 8192;
    unsigned m0 = 0, m1 = 0, m2 = 0, m3 = 0;
#pragma unroll 8
    for (int u = 0; u < 32; u++) {
        float4 v = p[u * 256 + threadIdx.x];
        m0 = max(m0, uabs_bits(v.x));
        m1 = max(m1, uabs_bits(v.y));
        m2 = max(m2, uabs_bits(v.z));
        m3 = max(m3, uabs_bits(v.w));
    }
    unsigned m = max(max(m0, m1), max(m2, m3));
#pragma unroll
    for (int off = 32; off > 0; off >>= 1)
        m = max(m, (unsigned)__shfl_down(m, off, 64));
    __shared__ unsigned sm[4];
    if ((threadIdx.x & 63) == 0) sm[threadIdx.x >> 6] = m;
    __syncthreads();
    if (threadIdx.x == 0)
        pmax[b] = max(max(sm[0], sm[1]), max(sm[2], sm[3]));
}

// ---- fused quantize: blocks [0,4096) lhs passthrough;
// blocks [4096,5120) rhs transpose, 256k x 64n tile -> full 256B-line writes.
__global__ __launch_bounds__(256) void quant_fused_kernel(
    const float* __restrict__ lhs, const float* __restrict__ rhs,
    unsigned char* __restrict__ qA, signed char* __restrict__ qBT,
    const unsigned* __restrict__ pmax) {
    const int N = MAT_N;
    const int t = threadIdx.x;
    int b = blockIdx.x;
    // [64 n-rows][256 k-bytes]; 16B chunks XOR-swizzled by (nr&15)
    __shared__ __align__(16) signed char smT[64 * 256];
    __shared__ unsigned red[4];
    __shared__ float s_sh;

    // Reduce this tensor's 512 partials -> scale (L2-hot, ~2KB)
    const int slot0 = (b < 4096) ? 0 : 512;
    unsigned mm = max(pmax[slot0 + t], pmax[slot0 + 256 + t]);
#pragma unroll
    for (int off = 32; off > 0; off >>= 1)
        mm = max(mm, (unsigned)__shfl_down(mm, off, 64));
    if ((t & 63) == 0) red[t >> 6] = mm;
    __syncthreads();
    if (t == 0) {
        unsigned f = max(max(red[0], red[1]), max(red[2], red[3]));
        s_sh = 127.0f / fmaxf(__uint_as_float(f), 1e-6f);
    }
    __syncthreads();
    const float s = s_sh;

    if (b < 4096) {
        const float4* x4 = (const float4*)lhs;
        unsigned* q4 = (unsigned*)qA;
        const int base4 = b * 1024;
#pragma unroll
        for (int u = 0; u < 4; u++) {
            int idx = base4 + u * 256 + t;
            float4 v = x4[idx];
            int a = min(127, max(-127, (int)rintf(v.x * s)));
            int bq = min(127, max(-127, (int)rintf(v.y * s)));
            int c = min(127, max(-127, (int)rintf(v.z * s)));
            int d = min(127, max(-127, (int)rintf(v.w * s)));
            q4[idx] = (unsigned)(a & 0xff) | ((unsigned)(bq & 0xff) << 8) |
                      ((unsigned)(c & 0xff) << 16) | ((unsigned)(d & 0xff) << 24);
        }
    } else {
        // rhs transpose: tile = 256 k-rows x 64 n-cols
        const int rb = b - 4096;          // 0..1023
        const int n0 = (rb & 63) * 64;    // column origin (floats)
        const int k0 = (rb >> 6) * 256;   // row origin
        const int mk = t >> 4;            // 0..15
        const int mn = t & 15;            // 0..15
        const float4* x4 = (const float4*)rhs;

        // Load all 16 float4 (4 sub-tiles x 4 rows) back-to-back
        float4 v[4][4];
#pragma unroll
        for (int ss = 0; ss < 4; ss++)
#pragma unroll
            for (int i = 0; i < 4; i++)
                v[ss][i] = x4[(size_t)(k0 + 64 * ss + 4 * mk + i) * (N / 4) +
                              (n0 >> 2) + mn];

        // Quantize + pack to 16 dwords
        unsigned w[4][4];
#pragma unroll
        for (int ss = 0; ss < 4; ss++)
#pragma unroll
            for (int i = 0; i < 4; i++) {
                int a = min(127, max(-127, (int)rintf(v[ss][i].x * s)));
                int bq = min(127, max(-127, (int)rintf(v[ss][i].y * s)));
                int c = min(127, max(-127, (int)rintf(v[ss][i].z * s)));
                int d = min(127, max(-127, (int)rintf(v[ss][i].w * s)));
                w[ss][i] =
                    (unsigned)(a & 0xff) | ((unsigned)(bq & 0xff) << 8) |
                    ((unsigned)(c & 0xff) << 16) | ((unsigned)(d & 0xff) << 24);
            }

        // 4x4 byte transpose per sub-tile; write dwords into swizzled smT.
        // Logical dword col = 16*ss + mk; chunk cq = col>>2, off = col&3.
        // Phys chunk = cq ^ (nr & 15).
#pragma unroll
        for (int ss = 0; ss < 4; ss++) {
            const int cq = 4 * ss + (mk >> 2);
            const int off = (mk & 3) * 4;
#pragma unroll
            for (int j = 0; j < 4; j++) {
                unsigned selj = (unsigned)j | ((unsigned)(4 + j) << 8) |
                                ((unsigned)j << 16) | ((unsigned)(4 + j) << 24);
                unsigned p01 = __builtin_amdgcn_perm(w[ss][1], w[ss][0], selj);
                unsigned p23 = __builtin_amdgcn_perm(w[ss][3], w[ss][2], selj);
                unsigned uj = __builtin_amdgcn_perm(p23, p01, 0x05040100u);
                const int nr = 4 * mn + j;
                *(unsigned*)(smT + nr * 256 + ((cq ^ (nr & 15)) << 4) + off) = uj;
            }
        }
        __syncthreads();

        // Read back b128 per (row, chunk); store full 256B lines to qBT
#pragma unroll
        for (int wq = 0; wq < 4; wq++) {
            const int idx = wq * 256 + t;
            const int nr = idx >> 4;
            const int cl = idx & 15;  // logical 16B chunk
            int4 val = *(const int4*)(smT + nr * 256 + ((cl ^ (nr & 15)) << 4));
            *(int4*)(qBT + (size_t)(n0 + nr) * N + k0 + cl * 16) = val;
        }
    }
}

#define MFMA_I8 __builtin_amdgcn_mfma_i32_32x32x32_i8
#define SBAR0() __builtin_amdgcn_sched_barrier(0)
#define BARRIER() __builtin_amdgcn_s_barrier()

// ---- int8 MFMA GEMM: C = A(MxK) * BT(NxK)^T
// 256x256 tile, BK=128, 8 waves (2Mx4N), 4 fine phases per K-tile.
// A: triple-buffered LDS (3x32KB), B: double-buffered (2x32KB) = 160KB.
// Counted pipeline: phase0 issues B(t+1), phase1 issues A(t+2); end-of-tile
// vmcnt(4) waits A(t+1)+B(t+1) and leaves A(t+2) in flight across the
// barrier. Chunk swizzle v(r)=(r^(r>>3))&7 on the global source side.
__global__ __launch_bounds__(512, 2) void gemm_i8_kernel(
    const signed char* __restrict__ A, const signed char* __restrict__ BT,
    float* __restrict__ C, const unsigned* __restrict__ pmax) {
    const int N = MAT_N;
    __shared__ __align__(16) signed char As[3][256 * 128];  // 96KB
    __shared__ __align__(16) signed char Bs[2][256 * 128];  // 64KB

    const int tid = threadIdx.x;
    const int wave = tid >> 6;   // 0..7
    const int lane = tid & 63;
    const int m32 = lane & 31;   // row/col within a 32-tile
    const int h = lane >> 5;     // k-half selector
    const int wm = wave >> 2;    // 0..1 -> 128-row half of the M-tile
    const int wn = wave & 3;     // 0..3 -> 64-col quarter of the N-tile

    // XCD-aware swizzle: 256 blocks -> 16x16 grid; XCD x owns a 4x8 rect.
    const int bid = blockIdx.x;
    const int xcd = bid & 7;
    const int bi = bid >> 3;                 // 0..31 within XCD
    const int by = (xcd >> 1) * 4 + (bi >> 3);
    const int bx = (xcd & 1) * 8 + (bi & 7);
    const int brow = by * 256;
    const int bcol = bx * 256;

    v16i acc[4][2] = {};

    // Staging: 2048 16B-chunks per 256x128 tile; 4 chunks/thread/operand.
    // LDS slot c=(r=c>>3, q'=c&7) receives global chunk q = q' ^ v(r).
    int gaoff[4], gboff[4], lofs[4];
#pragma unroll
    for (int u = 0; u < 4; u++) {
        int c = tid + 512 * u;
        int r = c >> 3;
        int q = (c & 7) ^ ((r ^ (r >> 3)) & 7);
        gaoff[u] = (brow + r) * N + q * 16;
        gboff[u] = (bcol + r) * N + q * 16;
        lofs[u] = c * 16;
    }

    // Fragment row bases + swizzle keys (k-invariant)
    int arow[4], av[4];
#pragma unroll
    for (int mi = 0; mi < 4; mi++) {
        int r = wm * 128 + mi * 32 + m32;
        arow[mi] = r * 128;
        av[mi] = (r ^ (r >> 3)) & 7;
    }
    int bro[2], bv[2];
#pragma unroll
    for (int nj = 0; nj < 2; nj++) {
        int r = wn * 64 + nj * 32 + m32;
        bro[nj] = r * 128;
        bv[nj] = (r ^ (r >> 3)) & 7;
    }

    // Prologue: issue A(0), B(0), A(1); wait A(0)+B(0), leave A(1) flying.
#pragma unroll
    for (int u = 0; u < 4; u++) async_copy16(A + gaoff[u], &As[0][lofs[u]]);
#pragma unroll
    for (int u = 0; u < 4; u++) async_copy16(BT + gboff[u], &Bs[0][lofs[u]]);
#pragma unroll
    for (int u = 0; u < 4; u++)
        async_copy16(A + gaoff[u] + 128, &As[1][lofs[u]]);
    asm volatile("s_waitcnt vmcnt(4)" ::: "memory");
    BARRIER();
    SBAR0();

    for (int t = 0; t < 32; ++t) {
        const int t3 = t % 3;
        const signed char* as_ = As[t3];
        const signed char* bs_ = Bs[t & 1];
        signed char* na = As[(t + 2) % 3];
        signed char* nb = Bs[(t & 1) ^ 1];
        const bool stB = (t < 31);  // stage B(t+1)
        const bool stA = (t < 30);  // stage A(t+2)

        // frag loads: k-slice s, lane half h -> 16B chunk q = 2s+h
#define LDA_(mi, s) (*(const v4i*)(as_ + arow[mi] + (((2 * (s) + h) ^ av[mi]) << 4)))
#define LDB_(nj, s) (*(const v4i*)(bs_ + bro[nj] + (((2 * (s) + h) ^ bv[nj]) << 4)))

        v4i bf00, bf01, bf10, bf11;

        // ---------- phase 0: s={0,1}, mi={0,1}; read B; issue stage B(t+1)
        {
            v4i a00 = LDA_(0, 0), a01 = LDA_(0, 1);
            v4i a10 = LDA_(1, 0), a11 = LDA_(1, 1);
            bf00 = LDB_(0, 0); bf01 = LDB_(0, 1);
            bf10 = LDB_(1, 0); bf11 = LDB_(1, 1);
            if (stB) {
#pragma unroll
                for (int u = 0; u < 4; u++)
                    async_copy16(BT + gboff[u] + (t + 1) * 128, nb + lofs[u]);
            }
            SBAR0();
            BARRIER();
            asm volatile("s_waitcnt lgkmcnt(0)" ::: "memory");
            SBAR0();
            __builtin_amdgcn_s_setprio(1);
            acc[0][0] = MFMA_I8(a00, bf00, acc[0][0], 0, 0, 0);
            acc[0][1] = MFMA_I8(a00, bf10, acc[0][1], 0, 0, 0);
            acc[1][0] = MFMA_I8(a10, bf00, acc[1][0], 0, 0, 0);
            acc[1][1] = MFMA_I8(a10, bf10, acc[1][1], 0, 0, 0);
            acc[0][0] = MFMA_I8(a01, bf01, acc[0][0], 0, 0, 0);
            acc[0][1] = MFMA_I8(a01, bf11, acc[0][1], 0, 0, 0);
            acc[1][0] = MFMA_I8(a11, bf01, acc[1][0], 0, 0, 0);
            acc[1][1] = MFMA_I8(a11, bf11, acc[1][1], 0, 0, 0);
            __builtin_amdgcn_s_setprio(0);
            BARRIER();
        }
        // ---------- phase 1: s={0,1}, mi={2,3}; reuse B; issue stage A(t+2)
        {
            v4i a20 = LDA_(2, 0), a21 = LDA_(2, 1);
            v4i a30 = LDA_(3, 0), a31 = LDA_(3, 1);
            if (stA) {
#pragma unroll
                for (int u = 0; u < 4; u++)
                    async_copy16(A + gaoff[u] + (t + 2) * 128, na + lofs[u]);
            }
            SBAR0();
            BARRIER();
            asm volatile("s_waitcnt lgkmcnt(0)" ::: "memory");
            SBAR0();
            __builtin_amdgcn_s_setprio(1);
            acc[2][0] = MFMA_I8(a20, bf00, acc[2][0], 0, 0, 0);
            acc[2][1] = MFMA_I8(a20, bf10, acc[2][1], 0, 0, 0);
            acc[3][0] = MFMA_I8(a30, bf00, acc[3][0], 0, 0, 0);
            acc[3][1] = MFMA_I8(a30, bf10, acc[3][1], 0, 0, 0);
            acc[2][0] = MFMA_I8(a21, bf01, acc[2][0], 0, 0, 0);
            acc[2][1] = MFMA_I8(a21, bf11, acc[2][1], 0, 0, 0);
            acc[3][0] = MFMA_I8(a31, bf01, acc[3][0], 0, 0, 0);
            acc[3][1] = MFMA_I8(a31, bf11, acc[3][1], 0, 0, 0);
            __builtin_amdgcn_s_setprio(0);
            BARRIER();
        }
        // ---------- phase 2: s={2,3}, mi={0,1}; read B
        {
            v4i a00 = LDA_(0, 2), a01 = LDA_(0, 3);
            v4i a10 = LDA_(1, 2), a11 = LDA_(1, 3);
            bf00 = LDB_(0, 2); bf01 = LDB_(0, 3);
            bf10 = LDB_(1, 2); bf11 = LDB_(1, 3);
            SBAR0();
            BARRIER();
            asm volatile("s_waitcnt lgkmcnt(0)" ::: "memory");
            SBAR0();
            __builtin_amdgcn_s_setprio(1);
            acc[0][0] = MFMA_I8(a00, bf00, acc[0][0], 0, 0, 0);
            acc[0][1] = MFMA_I8(a00, bf10, acc[0][1], 0, 0, 0);
            acc[1][0] = MFMA_I8(a10, bf00, acc[1][0], 0, 0, 0);
            acc[1][1] = MFMA_I8(a10, bf10, acc[1][1], 0, 0, 0);
            acc[0][0] = MFMA_I8(a01, bf01, acc[0][0], 0, 0, 0);
            acc[0][1] = MFMA_I8(a01, bf11, acc[0][1], 0, 0, 0);
            acc[1][0] = MFMA_I8(a11, bf01, acc[1][0], 0, 0, 0);
            acc[1][1] = MFMA_I8(a11, bf11, acc[1][1], 0, 0, 0);
            __builtin_amdgcn_s_setprio(0);
            BARRIER();
        }
        // ---------- phase 3: s={2,3}, mi={2,3}; reuse B; counted wait
        {
            v4i a20 = LDA_(2, 2), a21 = LDA_(2, 3);
            v4i a30 = LDA_(3, 2), a31 = LDA_(3, 3);
            SBAR0();
            BARRIER();
            asm volatile("s_waitcnt lgkmcnt(0)" ::: "memory");
            SBAR0();
            __builtin_amdgcn_s_setprio(1);
            acc[2][0] = MFMA_I8(a20, bf00, acc[2][0], 0, 0, 0);
            acc[2][1] = MFMA_I8(a20, bf10, acc[2][1], 0, 0, 0);
            acc[3][0] = MFMA_I8(a30, bf00, acc[3][0], 0, 0, 0);
            acc[3][1] = MFMA_I8(a30, bf10, acc[3][1], 0, 0, 0);
            acc[2][0] = MFMA_I8(a21, bf01, acc[2][0], 0, 0, 0);
            acc[2][1] = MFMA_I8(a21, bf11, acc[2][1], 0, 0, 0);
            acc[3][0] = MFMA_I8(a31, bf01, acc[3][0], 0, 0, 0);
            acc[3][1] = MFMA_I8(a31, bf11, acc[3][1], 0, 0, 0);
            __builtin_amdgcn_s_setprio(0);
            // Queue (oldest->newest): A(t+1)[<=4], B(t+1)[4], A(t+2)[4].
            // vmcnt(4): A(t+1), B(t+1) landed; A(t+2) stays in flight.
            if (t < 30) {
                asm volatile("s_waitcnt vmcnt(4)" ::: "memory");
            } else if (t == 30) {
                asm volatile("s_waitcnt vmcnt(0)" ::: "memory");
            }
            BARRIER();
            SBAR0();
        }
#undef LDA_
#undef LDB_
    }

    // Dequant scales from the 1024 partials; reduction scratch reuses
    // dead As space (final barrier above guarantees all reads done).
    unsigned* red = (unsigned*)&As[0][0];  // [0..7]=lhs, [8..15]=rhs
    unsigned ml = pmax[tid];
    unsigned mr = pmax[512 + tid];
#pragma unroll
    for (int off = 32; off > 0; off >>= 1) {
        ml = max(ml, (unsigned)__shfl_down(ml, off, 64));
        mr = max(mr, (unsigned)__shfl_down(mr, off, 64));
    }
    if (lane == 0) { red[wave] = ml; red[8 + wave] = mr; }
    __syncthreads();
    unsigned fl = red[0], fr = red[8];
#pragma unroll
    for (int k = 1; k < 8; k++) {
        fl = max(fl, red[k]);
        fr = max(fr, red[8 + k]);
    }
    const float bl = fmaxf(__uint_as_float(fl), 1e-6f);
    const float br = fmaxf(__uint_as_float(fr), 1e-6f);
    const float dq = bl * br * (1.0f / (127.0f * 127.0f));

    // C/D layout (32x32): col = lane&31, row = (reg&3) + 8*(reg>>2) + 4*h
#pragma unroll
    for (int mi = 0; mi < 4; mi++)
#pragma unroll
        for (int nj = 0; nj < 2; nj++) {
            const int col = bcol + wn * 64 + nj * 32 + m32;
#pragma unroll
            for (int reg = 0; reg < 16; reg++) {
                const int row =
                    brow + wm * 128 + mi * 32 + (reg & 3) + 8 * (reg >> 2) + 4 * h;
                C[(size_t)row * N + col] = (float)acc[mi][nj][reg] * dq;
            }
        }
}

extern "C" void kernel_launch(void* const* d_in, const int* in_sizes, int n_in,
                              void* d_out, int out_size, void* d_ws, size_t ws_size,
                              hipStream_t stream) {
    const float* lhs = (const float*)d_in[0];
    const float* rhs = (const float*)d_in[1];
    float* out = (float*)d_out;

    unsigned* pmax = (unsigned*)d_ws;  // 1024 partials (all written each call)
    signed char* qA = (signed char*)d_ws + 8192;
    signed char* qBT = qA + (size_t)MAT_N * MAT_N;

    absmax_partial_kernel<<<1024, 256, 0, stream>>>(
        (const float4*)lhs, (const float4*)rhs, pmax);
    quant_fused_kernel<<<5120, 256, 0, stream>>>(
        lhs, rhs, (unsigned char*)qA, qBT, pmax);
    gemm_i8_kernel<<<256, 512, 0, stream>>>(qA, qBT, out, pmax);
}